// Round 9
// baseline (102.398 us; speedup 1.0000x reference)
//
#include <hip/hip_runtime.h>
#include <hip/hip_bf16.h>

typedef __attribute__((ext_vector_type(8))) short bf16x8;
typedef __attribute__((ext_vector_type(4))) float f32x4;

#define WR_OFF   27557888   // Wr right after Xp (16*58*58*256*2B) in d_ws
// S (diag sums, 580608 floats = 2.32MB) overlays Xp start: consumed by wsynth
// BEFORE pad (which writes Xp). Stream-ordered.

#define BAND 24576          // one X band buffer: [slot4][row6][col64][16B]

// ---------------- per-level circulant diagonal sums -------------------------
// S[level][q][p][d][tap] = sum_{t<b} W[q*b+t][p*b + ((t+d)&(b-1))][tap]
__global__ void diagsum_kernel(const float* __restrict__ W, float* __restrict__ S) {
    int t = blockIdx.x * 256 + threadIdx.x;   // 64512 threads exactly
    int idx, n, lvlOff;
    if (t < 32768)      { idx = 1; n = t;          lvlOff = 0; }
    else if (t < 49152) { idx = 2; n = t - 32768;  lvlOff = 294912; }
    else if (t < 57344) { idx = 3; n = t - 49152;  lvlOff = 442368; }
    else if (t < 61440) { idx = 4; n = t - 57344;  lvlOff = 516096; }
    else if (t < 63488) { idx = 5; n = t - 61440;  lvlOff = 552960; }
    else                { idx = 6; n = t - 63488;  lvlOff = 571392; }
    int b = 1 << idx;
    int d = n & (b - 1);
    int qp = n >> idx;
    int p = qp & ((256 >> idx) - 1);
    int q = qp >> (8 - idx);
    float s[9];
    #pragma unroll
    for (int tp = 0; tp < 9; ++tp) s[tp] = 0.f;
    for (int tt = 0; tt < b; ++tt) {
        const float* wp = W + ((size_t)((q * b + tt) * 256 + p * b + ((tt + d) & (b - 1)))) * 9;
        #pragma unroll
        for (int tp = 0; tp < 9; ++tp) s[tp] += wp[tp];
    }
    float* o = S + (size_t)lvlOff + (size_t)n * 9;
    #pragma unroll
    for (int tp = 0; tp < 9; ++tp) o[tp] = s[tp];
}

// ---------------- weight synthesis: softmax + gather of diag sums -----------
// Output layout = conv fragment layout: elem(tap,o,c) =
//   tap*65536 + (c>>5)*8192 + ((c>>3)&3)*2048 + o*8 + (c&7)
__global__ void wsynth_kernel(const float* __restrict__ W,
                              const float* __restrict__ alphas,
                              const float* __restrict__ gumbels,
                              const float* __restrict__ S,
                              __hip_bfloat16* __restrict__ Wr) {
    int tid = blockIdx.x * 256 + threadIdx.x;   // 65536 threads: one per (o,i)
    int o = tid >> 8, i = tid & 255;

    float a[7]; float mx = -1e30f;
    for (int j = 0; j < 7; ++j) { a[j] = alphas[j] + 1.0e-4f * gumbels[j]; mx = fmaxf(mx, a[j]); }
    float s = 0.f;
    for (int j = 0; j < 7; ++j) { a[j] = __expf(a[j] - mx); s += a[j]; }
    float invs = 1.0f / s;
    for (int j = 0; j < 7; ++j) a[j] *= invs;

    float acc[9];
    const float* w0 = W + ((size_t)(o * 256 + i)) * 9;
    #pragma unroll
    for (int t = 0; t < 9; ++t) acc[t] = a[0] * w0[t];

    const int lvlOff[7] = {0, 0, 294912, 442368, 516096, 552960, 571392};
    int dif = i - o;
    #pragma unroll
    for (int idx = 1; idx < 7; ++idx) {
        int b = 1 << idx;
        int q = o >> idx, p = i >> idx, d = dif & (b - 1);
        int n = ((q * (256 >> idx) + p) << idx) + d;
        const float* sp = S + lvlOff[idx] + (size_t)n * 9;
        float sc = a[idx] / (float)b;
        #pragma unroll
        for (int tp = 0; tp < 9; ++tp) acc[tp] += sc * sp[tp];
    }
    const size_t eb = (size_t)(i >> 5) * 8192 + ((i >> 3) & 3) * 2048 + o * 8 + (i & 7);
    #pragma unroll
    for (int tp = 0; tp < 9; ++tp)
        Wr[(size_t)tp * 65536 + eb] = __float2bfloat16(acc[tp]);
}

// ------- NCHW fp32 -> zero-padded NHWC bf16 [16][58][58][256] + border ------
__global__ void pad_nhwc_kernel(const float* __restrict__ x,
                                __hip_bfloat16* __restrict__ Xp) {
    // fused border zeroing: 933888 border elems over 802816 threads (1-2 each)
    {
        int bl = (blockIdx.z * 4 + blockIdx.y) * 49 + blockIdx.x;  // 0..3135
        int L = bl * 256 + threadIdx.x;
        for (int e = L; e < 933888; e += 802816) {
            int c = e & 255;
            int pp = e >> 8;
            int b = pp / 228;
            int p = pp - b * 228;
            int y, xx;
            if (p < 58)       { y = 0;             xx = p; }
            else if (p < 116) { y = 57;            xx = p - 58; }
            else if (p < 172) { y = 1 + (p - 116); xx = 0; }
            else              { y = 1 + (p - 172); xx = 57; }
            Xp[((size_t)(b * 58 + y) * 58 + xx) * 256 + c] = __float2bfloat16(0.f);
        }
    }
    __shared__ float t[64][65];
    int p0 = blockIdx.x * 64;       // pixel chunk within image (3136/64 = 49)
    int c0 = blockIdx.y * 64;       // channel chunk
    int b  = blockIdx.z;            // image
    int lane = threadIdx.x & 63;
    int grp  = threadIdx.x >> 6;    // 0..3

    const float* src = x + ((size_t)(b * 256 + c0)) * 3136 + p0;
    #pragma unroll
    for (int it = 0; it < 16; ++it) {
        int c = it * 4 + grp;
        t[c][lane] = src[(size_t)c * 3136 + lane];   // coalesced reads
    }
    __syncthreads();
    #pragma unroll
    for (int it = 0; it < 16; ++it) {
        int pl = it * 4 + grp;
        int P = p0 + pl;
        int y = P / 56, xx = P - y * 56;
        Xp[(((size_t)(b * 58 + y + 1)) * 58 + (xx + 1)) * 256 + c0 + lane] =
            __float2bfloat16(t[lane][pl]);           // coalesced 128B writes
    }
}

// -------- conv: 224px x 128och tile, grid 448, 2 blocks/CU, JIT loads -------
__device__ __forceinline__ void gload16(const __hip_bfloat16* g, char* l) {
    __builtin_amdgcn_global_load_lds(
        (const __attribute__((address_space(1))) void*)g,
        (__attribute__((address_space(3))) void*)l, 16, 0, 0);
}

// One c-chunk (32 ch): 9 tap-steps. Per step: JIT A (global, L2), JIT B (LDS),
// 14 MFMA. Band for next chunk staged at r==3. One __syncthreads per chunk.
template<bool LAST>
__device__ __forceinline__ void chunk_body(
    int cc, char* smem, const char* aBase,
    const int (&bOff)[7], const __hip_bfloat16* const (&xSrc)[3],
    int tid, f32x4 (&acc)[2][7])
{
    const char* xb = smem + (cc & 1) * BAND;
    #pragma unroll
    for (int r = 0; r < 9; ++r) {
        // 1. JIT A-frags for this step (L2-resident Wr; TLP hides latency)
        const int aoff = r * 131072 + cc * 16384;
        bf16x8 af0 = *(const bf16x8*)(aBase + aoff);
        bf16x8 af1 = *(const bf16x8*)(aBase + aoff + 256);
        // 2. stage next chunk's band (buffer (cc+1)&1 free since last barrier)
        if (!LAST && r == 3) {
            char* d = smem + ((cc + 1) & 1) * BAND + tid * 16;
            #pragma unroll
            for (int it = 0; it < 3; ++it)
                gload16(xSrc[it] + (cc + 1) * 32, d + it * 8192);
        }
        // 3. JIT B-frags from LDS
        const int dy = r / 3 - 1, dx = r % 3 - 1;
        const int timm = (dy * 64 + dx) * 16;
        bf16x8 bfv[7];
        #pragma unroll
        for (int mf = 0; mf < 7; ++mf)
            bfv[mf] = *(const bf16x8*)(xb + bOff[mf] + timm);
        // 4. MFMA cluster
        __builtin_amdgcn_s_setprio(1);
        #pragma unroll
        for (int mf = 0; mf < 7; ++mf) {
            acc[0][mf] = __builtin_amdgcn_mfma_f32_16x16x32_bf16(af0, bfv[mf], acc[0][mf], 0, 0, 0);
            acc[1][mf] = __builtin_amdgcn_mfma_f32_16x16x32_bf16(af1, bfv[mf], acc[1][mf], 0, 0, 0);
        }
        __builtin_amdgcn_s_setprio(0);
        // 5. chunk boundary: drain (vmcnt0+lgkm0) + barrier -> band visible
        if (r == 8 && !LAST) __syncthreads();
    }
}

__global__ __launch_bounds__(512, 4) void conv_kernel(
        const __hip_bfloat16* __restrict__ Xp,
        const __hip_bfloat16* __restrict__ Wr,
        float* __restrict__ out) {
    __shared__ char smem[2 * BAND];

    const int tid = threadIdx.x;
    const int w = tid >> 6, lane = tid & 63, l15 = lane & 15, q = lane >> 4;
    const int bid = blockIdx.x;            // 448 blocks: (bid%224)=row-tile, (bid/224)=och half
    const int mt  = bid % 224;
    const int n0  = (bid / 224) * 128;     // och base; pair (bid, bid+224) same XCD
    const int bimg = mt / 14;
    const int y0 = (mt - bimg * 14) * 4;

    const int wn = (w & 3) << 5;           // wave och base within half (4 waves x 32)
    const int wm = (w >> 2) * 112;         // wave pixel base (2 waves x 112)

    // A-frag per-lane base (bytes into Wr): [tap][cc][q][och][8]
    const char* aBase = (const char*)Wr + q * 4096 + (n0 + wn + l15) * 16;

    // X band staging: 3 chunks/thread; chunk = tid + it*512 -> (slot, row, xcol)
    const __hip_bfloat16* xSrc[3];
    #pragma unroll
    for (int it = 0; it < 3; ++it) {
        int chunk = tid + it * 512;
        int slot = chunk / 384;
        int rem  = chunk - slot * 384;
        int row = rem >> 6, xcol = rem & 63;   // xcol>=58 reads in-bounds garbage (unused)
        xSrc[it] = Xp + (((size_t)(bimg * 58 + y0 + row)) * 58 + xcol) * 256 + slot * 8;
    }

    // B-frag read offsets (bytes); conflict-free [slot][row][16B] layout
    int bOff[7];
    #pragma unroll
    for (int mf = 0; mf < 7; ++mf) {
        int p = wm + mf * 16 + l15;            // local pixel 0..223
        int y = p / 56, xx = p - y * 56;
        bOff[mf] = q * 6144 + ((y + 1) * 64 + (xx + 1)) * 16;
    }

    f32x4 acc[2][7];
    #pragma unroll
    for (int a1 = 0; a1 < 2; ++a1)
        #pragma unroll
        for (int a2 = 0; a2 < 7; ++a2)
            acc[a1][a2] = (f32x4){0.f, 0.f, 0.f, 0.f};

    // prologue: band 0 into buffer 0
    {
        char* d = smem + tid * 16;
        #pragma unroll
        for (int it = 0; it < 3; ++it) gload16(xSrc[it], d + it * 8192);
    }
    __syncthreads();

    for (int cc = 0; cc < 7; ++cc)
        chunk_body<false>(cc, smem, aBase, bOff, xSrc, tid, acc);
    chunk_body<true>(7, smem, aBase, bOff, xSrc, tid, acc);

    // epilogue: och from (n0,wn,q,nf,rr), pixel from (wm,mf,l15); 64B runs
    const int nb = n0 + wn + q * 4;
    const size_t obB = (size_t)bimg * 256 * 3136;
    #pragma unroll
    for (int mf = 0; mf < 7; ++mf) {
        int pm = y0 * 56 + wm + mf * 16 + l15;
        #pragma unroll
        for (int nf = 0; nf < 2; ++nf) {
            #pragma unroll
            for (int rr = 0; rr < 4; ++rr)
                out[obB + (size_t)(nb + nf * 16 + rr) * 3136 + pm] = acc[nf][mf][rr];
        }
    }
}

extern "C" void kernel_launch(void* const* d_in, const int* in_sizes, int n_in,
                              void* d_out, int out_size, void* d_ws, size_t ws_size,
                              hipStream_t stream) {
    const float* x       = (const float*)d_in[0];
    const float* weight  = (const float*)d_in[1];
    const float* alphas  = (const float*)d_in[2];
    const float* gumbels = (const float*)d_in[3];
    float* out = (float*)d_out;

    __hip_bfloat16* Xp = (__hip_bfloat16*)d_ws;
    float*          S  = (float*)d_ws;            // overlays Xp; used pre-pad
    __hip_bfloat16* Wr = (__hip_bfloat16*)((char*)d_ws + WR_OFF);

    hipLaunchKernelGGL(diagsum_kernel,  dim3(252),       dim3(256), 0, stream,
                       weight, S);
    hipLaunchKernelGGL(wsynth_kernel,   dim3(256),       dim3(256), 0, stream,
                       weight, alphas, gumbels, S, Wr);
    hipLaunchKernelGGL(pad_nhwc_kernel, dim3(49, 4, 16), dim3(256), 0, stream,
                       x, Xp);
    hipLaunchKernelGGL(conv_kernel,     dim3(448),       dim3(512), 0, stream,
                       Xp, Wr, out);
}

// Round 10
// 97.121 us; speedup vs baseline: 1.0543x; 1.0543x over previous
//
#include <hip/hip_runtime.h>
#include <hip/hip_bf16.h>

typedef __attribute__((ext_vector_type(8))) short bf16x8;
typedef __attribute__((ext_vector_type(4))) float f32x4;

#define WR_OFF   27557888   // Wr right after Xp (16*58*58*256*2B) in d_ws
// S (diag sums, 580608 floats = 2.32MB) overlays Xp start: consumed by wsynth
// BEFORE pad (which writes Xp). Stream-ordered.

#define BAND 24576          // one X band buffer: [slot4][row6][col64][16B]

// ---------------- per-level circulant diagonal sums -------------------------
// S[level][q][p][d][tap] = sum_{t<b} W[q*b+t][p*b + ((t+d)&(b-1))][tap]
__global__ void diagsum_kernel(const float* __restrict__ W, float* __restrict__ S) {
    int t = blockIdx.x * 256 + threadIdx.x;   // 64512 threads exactly
    int idx, n, lvlOff;
    if (t < 32768)      { idx = 1; n = t;          lvlOff = 0; }
    else if (t < 49152) { idx = 2; n = t - 32768;  lvlOff = 294912; }
    else if (t < 57344) { idx = 3; n = t - 49152;  lvlOff = 442368; }
    else if (t < 61440) { idx = 4; n = t - 57344;  lvlOff = 516096; }
    else if (t < 63488) { idx = 5; n = t - 61440;  lvlOff = 552960; }
    else                { idx = 6; n = t - 63488;  lvlOff = 571392; }
    int b = 1 << idx;
    int d = n & (b - 1);
    int qp = n >> idx;
    int p = qp & ((256 >> idx) - 1);
    int q = qp >> (8 - idx);
    float s[9];
    #pragma unroll
    for (int tp = 0; tp < 9; ++tp) s[tp] = 0.f;
    for (int tt = 0; tt < b; ++tt) {
        const float* wp = W + ((size_t)((q * b + tt) * 256 + p * b + ((tt + d) & (b - 1)))) * 9;
        #pragma unroll
        for (int tp = 0; tp < 9; ++tp) s[tp] += wp[tp];
    }
    float* o = S + (size_t)lvlOff + (size_t)n * 9;
    #pragma unroll
    for (int tp = 0; tp < 9; ++tp) o[tp] = s[tp];
}

// ---------------- weight synthesis: softmax + gather of diag sums -----------
// Output layout = conv fragment layout: elem(tap,o,c) =
//   tap*65536 + (c>>5)*8192 + ((c>>3)&3)*2048 + o*8 + (c&7)
__global__ void wsynth_kernel(const float* __restrict__ W,
                              const float* __restrict__ alphas,
                              const float* __restrict__ gumbels,
                              const float* __restrict__ S,
                              __hip_bfloat16* __restrict__ Wr) {
    int tid = blockIdx.x * 256 + threadIdx.x;   // 65536 threads: one per (o,i)
    int o = tid >> 8, i = tid & 255;

    float a[7]; float mx = -1e30f;
    for (int j = 0; j < 7; ++j) { a[j] = alphas[j] + 1.0e-4f * gumbels[j]; mx = fmaxf(mx, a[j]); }
    float s = 0.f;
    for (int j = 0; j < 7; ++j) { a[j] = __expf(a[j] - mx); s += a[j]; }
    float invs = 1.0f / s;
    for (int j = 0; j < 7; ++j) a[j] *= invs;

    float acc[9];
    const float* w0 = W + ((size_t)(o * 256 + i)) * 9;
    #pragma unroll
    for (int t = 0; t < 9; ++t) acc[t] = a[0] * w0[t];

    const int lvlOff[7] = {0, 0, 294912, 442368, 516096, 552960, 571392};
    int dif = i - o;
    #pragma unroll
    for (int idx = 1; idx < 7; ++idx) {
        int b = 1 << idx;
        int q = o >> idx, p = i >> idx, d = dif & (b - 1);
        int n = ((q * (256 >> idx) + p) << idx) + d;
        const float* sp = S + lvlOff[idx] + (size_t)n * 9;
        float sc = a[idx] / (float)b;
        #pragma unroll
        for (int tp = 0; tp < 9; ++tp) acc[tp] += sc * sp[tp];
    }
    const size_t eb = (size_t)(i >> 5) * 8192 + ((i >> 3) & 3) * 2048 + o * 8 + (i & 7);
    #pragma unroll
    for (int tp = 0; tp < 9; ++tp)
        Wr[(size_t)tp * 65536 + eb] = __float2bfloat16(acc[tp]);
}

// ------- NCHW fp32 -> zero-padded NHWC bf16 [16][58][58][256] + border ------
__global__ void pad_nhwc_kernel(const float* __restrict__ x,
                                __hip_bfloat16* __restrict__ Xp) {
    // fused border zeroing: 933888 border elems over 802816 threads (1-2 each)
    {
        int bl = (blockIdx.z * 4 + blockIdx.y) * 49 + blockIdx.x;  // 0..3135
        int L = bl * 256 + threadIdx.x;
        for (int e = L; e < 933888; e += 802816) {
            int c = e & 255;
            int pp = e >> 8;
            int b = pp / 228;
            int p = pp - b * 228;
            int y, xx;
            if (p < 58)       { y = 0;             xx = p; }
            else if (p < 116) { y = 57;            xx = p - 58; }
            else if (p < 172) { y = 1 + (p - 116); xx = 0; }
            else              { y = 1 + (p - 172); xx = 57; }
            Xp[((size_t)(b * 58 + y) * 58 + xx) * 256 + c] = __float2bfloat16(0.f);
        }
    }
    __shared__ float t[64][65];
    int p0 = blockIdx.x * 64;       // pixel chunk within image (3136/64 = 49)
    int c0 = blockIdx.y * 64;       // channel chunk
    int b  = blockIdx.z;            // image
    int lane = threadIdx.x & 63;
    int grp  = threadIdx.x >> 6;    // 0..3

    const float* src = x + ((size_t)(b * 256 + c0)) * 3136 + p0;
    #pragma unroll
    for (int it = 0; it < 16; ++it) {
        int c = it * 4 + grp;
        t[c][lane] = src[(size_t)c * 3136 + lane];   // coalesced reads
    }
    __syncthreads();
    #pragma unroll
    for (int it = 0; it < 16; ++it) {
        int pl = it * 4 + grp;
        int P = p0 + pl;
        int y = P / 56, xx = P - y * 56;
        Xp[(((size_t)(b * 58 + y + 1)) * 58 + (xx + 1)) * 256 + c0 + lane] =
            __float2bfloat16(t[lane][pl]);           // coalesced 128B writes
    }
}

// -------- conv: 224px x 256och tile, 4 waves, wave = 128och x 112px ---------
__device__ __forceinline__ void gload16(const __hip_bfloat16* g, char* l) {
    __builtin_amdgcn_global_load_lds(
        (const __attribute__((address_space(1))) void*)g,
        (__attribute__((address_space(3))) void*)l, 16, 0, 0);
}

// Two c-chunks (cc = 2cp+u, u unrolled so reg-dbuf parity is compile-time).
// Per step r: prefetch A(r+1) global->reg (8 frags), prefetch B(r+1) LDS->reg
// (7 frags), sched_barrier pin, 56 MFMA on [cur]. Band staged r==3/4; barrier
// at end of r==7 (drains stage); r==8 prefetches from the fresh band.
template<bool LAST>
__device__ __forceinline__ void chunk_pair(
    int cp, char* smem, const char* aBase,
    const int (&bOff)[7], const __hip_bfloat16* const (&xSrc)[6],
    int tid, bf16x8 (&afr)[2][8], bf16x8 (&bfv)[2][7], f32x4 (&acc)[8][7])
{
    #pragma unroll
    for (int u = 0; u < 2; ++u) {
        const int cc = 2 * cp + u;
        const char* xb = smem + u * BAND;          // cc&1 == u (2cp even)
        #pragma unroll
        for (int r = 0; r < 9; ++r) {
            const int cur = (u + r) & 1, nxt = cur ^ 1;
            // 1. prefetch A-frags for next step (L2-resident Wr)
            if (!(LAST && u == 1 && r == 8)) {
                const int tapn = (r == 8) ? 0 : r + 1;
                const int aoff = tapn * 131072 + (cc + (r == 8 ? 1 : 0)) * 16384;
                #pragma unroll
                for (int nf = 0; nf < 8; ++nf)
                    afr[nxt][nf] = *(const bf16x8*)(aBase + aoff + nf * 256);
            }
            // 2. stage next chunk's band: 3 gloads at r==3, 3 at r==4
            if (!(LAST && u == 1) && (r == 3 || r == 4)) {
                const int i0 = (r == 3) ? 0 : 3;
                char* d = smem + (u ^ 1) * BAND + tid * 16;
                #pragma unroll
                for (int it = 0; it < 3; ++it)
                    gload16(xSrc[i0 + it] + (cc + 1) * 32, d + (i0 + it) * 4096);
            }
            // 3. prefetch B-frags for next step (reg double-buffer)
            if (r < 8) {
                const int tapn = r + 1;
                const int timn = ((tapn / 3 - 1) * 64 + (tapn % 3 - 1)) * 16;
                #pragma unroll
                for (int mf = 0; mf < 7; ++mf)
                    bfv[nxt][mf] = *(const bf16x8*)(xb + bOff[mf] + timn);
            } else if (!(LAST && u == 1)) {
                const int timn = (-64 - 1) * 16;   // tap 0
                const char* xb2 = smem + (u ^ 1) * BAND;
                #pragma unroll
                for (int mf = 0; mf < 7; ++mf)
                    bfv[nxt][mf] = *(const bf16x8*)(xb2 + bOff[mf] + timn);
            }
            // pin: prefetches stay above the MFMA cluster
            __builtin_amdgcn_sched_barrier(0);
            // 4. MFMA cluster on current-step registers (56 MFMA)
            #pragma unroll
            for (int nf = 0; nf < 8; ++nf)
                #pragma unroll
                for (int mf = 0; mf < 7; ++mf)
                    acc[nf][mf] = __builtin_amdgcn_mfma_f32_16x16x32_bf16(
                        afr[cur][nf], bfv[cur][mf], acc[nf][mf], 0, 0, 0);
            // 5. chunk barrier at end of r==7: drains stage gloads (vmcnt0
            //    implicit) so r==8 reads the fresh band safely.
            if (r == 7 && !(LAST && u == 1)) __syncthreads();
        }
    }
}

__global__ __launch_bounds__(256, 1) void conv_kernel(
        const __hip_bfloat16* __restrict__ Xp,
        const __hip_bfloat16* __restrict__ Wr,
        float* __restrict__ out) {
    __shared__ char smem[2 * BAND];

    const int tid = threadIdx.x;
    const int w = tid >> 6, lane = tid & 63, l15 = lane & 15, q = lane >> 4;
    const int bid = blockIdx.x;            // 224 blocks: 14 per image, 4 rows
    const int bimg = bid / 14;
    const int y0 = (bid - bimg * 14) * 4;

    const int wn = (w & 1) << 7;           // wave och base (2 groups x 128)
    const int wm = (w >> 1) * 112;         // wave pixel base (2 groups x 112)

    // A-frag per-lane base (bytes into Wr): [tap][cc][q][och][8]
    const char* aBase = (const char*)Wr + q * 4096 + (wn + l15) * 16;

    // X band staging: 6 chunks/thread; chunk = tid + it*256 -> (slot, row, xcol)
    const __hip_bfloat16* xSrc[6];
    #pragma unroll
    for (int it = 0; it < 6; ++it) {
        int chunk = tid + it * 256;
        int slot = chunk / 384;
        int rem  = chunk - slot * 384;
        int row = rem >> 6, xcol = rem & 63;   // xcol>=58 reads in-bounds garbage (unused)
        xSrc[it] = Xp + (((size_t)(bimg * 58 + y0 + row)) * 58 + xcol) * 256 + slot * 8;
    }

    // B-frag read offsets (bytes); conflict-free [slot][row][16B] layout
    int bOff[7];
    #pragma unroll
    for (int mf = 0; mf < 7; ++mf) {
        int p = wm + mf * 16 + l15;            // local pixel 0..223
        int y = p / 56, xx = p - y * 56;
        bOff[mf] = q * 6144 + ((y + 1) * 64 + (xx + 1)) * 16;
    }

    f32x4 acc[8][7];
    #pragma unroll
    for (int a1 = 0; a1 < 8; ++a1)
        #pragma unroll
        for (int a2 = 0; a2 < 7; ++a2)
            acc[a1][a2] = (f32x4){0.f, 0.f, 0.f, 0.f};

    bf16x8 afr[2][8], bfv[2][7];

    // prologue: band 0 into buffer 0; A+B frags for step (tap0, cc0)
    {
        char* d = smem + tid * 16;
        #pragma unroll
        for (int it = 0; it < 6; ++it) gload16(xSrc[it], d + it * 4096);
    }
    #pragma unroll
    for (int nf = 0; nf < 8; ++nf)
        afr[0][nf] = *(const bf16x8*)(aBase + nf * 256);
    __syncthreads();   // drains vmcnt (band 0) + all waves ready
    {
        const int timm = (-64 - 1) * 16;       // tap 0: dy=-1, dx=-1
        #pragma unroll
        for (int mf = 0; mf < 7; ++mf)
            bfv[0][mf] = *(const bf16x8*)(smem + bOff[mf] + timm);
    }

    for (int cp = 0; cp < 3; ++cp)
        chunk_pair<false>(cp, smem, aBase, bOff, xSrc, tid, afr, bfv, acc);
    chunk_pair<true>(3, smem, aBase, bOff, xSrc, tid, afr, bfv, acc);

    // epilogue: och from (wn,nf,q,rr), pixel from (wm,mf,l15); 64B runs
    const int nb = wn + q * 4;
    const size_t obB = (size_t)bimg * 256 * 3136;
    #pragma unroll
    for (int mf = 0; mf < 7; ++mf) {
        int pm = y0 * 56 + wm + mf * 16 + l15;
        #pragma unroll
        for (int nf = 0; nf < 8; ++nf) {
            #pragma unroll
            for (int rr = 0; rr < 4; ++rr)
                out[obB + (size_t)(nb + nf * 16 + rr) * 3136 + pm] = acc[nf][mf][rr];
        }
    }
}

extern "C" void kernel_launch(void* const* d_in, const int* in_sizes, int n_in,
                              void* d_out, int out_size, void* d_ws, size_t ws_size,
                              hipStream_t stream) {
    const float* x       = (const float*)d_in[0];
    const float* weight  = (const float*)d_in[1];
    const float* alphas  = (const float*)d_in[2];
    const float* gumbels = (const float*)d_in[3];
    float* out = (float*)d_out;

    __hip_bfloat16* Xp = (__hip_bfloat16*)d_ws;
    float*          S  = (float*)d_ws;            // overlays Xp; used pre-pad
    __hip_bfloat16* Wr = (__hip_bfloat16*)((char*)d_ws + WR_OFF);

    hipLaunchKernelGGL(diagsum_kernel,  dim3(252),       dim3(256), 0, stream,
                       weight, S);
    hipLaunchKernelGGL(wsynth_kernel,   dim3(256),       dim3(256), 0, stream,
                       weight, alphas, gumbels, S, Wr);
    hipLaunchKernelGGL(pad_nhwc_kernel, dim3(49, 4, 16), dim3(256), 0, stream,
                       x, Xp);
    hipLaunchKernelGGL(conv_kernel,     dim3(224),       dim3(256), 0, stream,
                       Xp, Wr, out);
}